// Round 2
// baseline (346.298 us; speedup 1.0000x reference)
//
#include <hip/hip_runtime.h>
#include <hip/hip_bf16.h>
#include <math.h>

typedef int   v4i __attribute__((ext_vector_type(4)));
typedef float v4f __attribute__((ext_vector_type(4)));

#define B_DIM   256
#define IN_DIM  1024
#define H4      4096
#define NPLANE  4
#define WELEM   (NPLANE * IN_DIM * H4)   // 16777216 per weight tensor
#define XELEM   (B_DIM * IN_DIM)         // 262144

// ---- ws layout ----
#define WS_THRESH_OFF 64
#define WS_X_OFF      (64 + 262144)
#define WS_CMP_OFF    (64 + 262144 + 1048576)

// CK-style barrier: orders LDS ops but does NOT drain vmcnt -> global prefetch
// loads stay in flight across the barrier.
#define SYNC_LDS() __asm__ volatile("s_waitcnt lgkmcnt(0)\n\ts_barrier" ::: "memory")

// ---------------- Pass A1: global maxes ----------------
__global__ void k_max(const float* __restrict__ wih, const float* __restrict__ whh,
                      const float* __restrict__ bih, const float* __restrict__ bhh,
                      float* __restrict__ outm) {
  int b = blockIdx.x, t = threadIdx.x;
  const v4f* p; int slot; size_t base; int iters;
  if (b < 2048)      { p = (const v4f*)wih; slot = 0; base = (size_t)b * 2048;          iters = 8;  }
  else if (b < 4096) { p = (const v4f*)whh; slot = 1; base = (size_t)(b - 2048) * 2048; iters = 8;  }
  else if (b == 4096){ p = (const v4f*)bih; slot = 2; base = 0;                          iters = 16; }
  else               { p = (const v4f*)bhh; slot = 3; base = 0;                          iters = 16; }
  float m = -3.4e38f;
#pragma unroll 4
  for (int it = 0; it < iters; ++it) {
    v4f v = p[base + (size_t)it * 256 + t];
    m = fmaxf(m, fmaxf(fmaxf(v.x, v.y), fmaxf(v.z, v.w)));
  }
#pragma unroll
  for (int off = 32; off >= 1; off >>= 1) m = fmaxf(m, __shfl_down(m, off, 64));
  __shared__ float sm[4];
  int w = t >> 6, ln = t & 63;
  if (ln == 0) sm[w] = m;
  __syncthreads();
  if (t == 0) {
    m = fmaxf(fmaxf(sm[0], sm[1]), fmaxf(sm[2], sm[3]));
    atomicMax((int*)&outm[slot], __float_as_int(m));  // maxes > 0 for gaussian data
  }
}

// ---------------- Pass A2: input bit-planes + bias thresholds ----------------
__global__ void k_prep(const float* __restrict__ input,
                       const float* __restrict__ bih, const float* __restrict__ bhh,
                       const float* __restrict__ ebih, const float* __restrict__ ebhh,
                       const float* __restrict__ a1p, const float* __restrict__ maxm,
                       double* __restrict__ thresh, signed char* __restrict__ X) {
  int gid = blockIdx.x * 256 + threadIdx.x;
  if (blockIdx.x < 1024) {                       // X part: 262144 elements
    float a1 = a1p[0];
    float x = input[gid];
    float t = fabsf(x), u = fabsf(t - a1);
    float sg = (x > 0.f) ? 0.5f : ((x < 0.f) ? -0.5f : 0.f);
    float p = sg * ((t - u) + a1);
    float inp01 = (p + a1) / (a1 * 2.0f);
    float q = rintf(15.0f * inp01);
    int qi = (int)q;
#pragma unroll
    for (int pl = 0; pl < 4; ++pl)
      X[pl * XELEM + gid] = (signed char)((qi >> (3 - pl)) & 1);
  } else {                                       // thresh part: 32768 elements
    int i2 = gid - 262144;                       // s*16384 + n*4096 + col
    int s = i2 >> 14; int r = i2 & 16383;
    const float* bp = s ? bhh : bih;
    const float* ep = s ? ebhh : ebih;
    float mb = maxm[2 + s];
    float bv = bp[r], ev = ep[r];
    float xc = fminf(fmaxf(bv, -0.9921875f), 0.9921875f);
    float qv = rintf(xc * 128.f) * 0.0078125f;
    float noise = (ev * mb) * 0.1f;
    float beff = bv + ((qv - bv) + noise);
    thresh[i2] = 0.5 - (double)beff;
  }
}

// ---------------- Pass B: exact digit-GEMM, depth-2 prefetch ----------------
// grid: x = ntile (128 tiles of 32 cols), y = sp (s*4 + plane, 8)
// block: 512 threads = 8 waves; wave w covers output rows [w*32, w*32+32)
__global__ __launch_bounds__(512, 4) void k_gemm(
    const float* __restrict__ Wih, const float* __restrict__ Whh,
    const float* __restrict__ Eih, const float* __restrict__ Ehh,
    const float* __restrict__ maxm, const double* __restrict__ thresh,
    const signed char* __restrict__ X, unsigned char* __restrict__ cmp) {
  const int ntile = blockIdx.x;
  const int sp = blockIdx.y;
  const int s = sp >> 2, plane = sp & 3;
  const float* W = s ? Whh : Wih;
  const float* E = s ? Ehh : Eih;
  const float maxw = maxm[s];

  const int tid = threadIdx.x;
  const int wave = tid >> 6, lane = tid & 63, quad = lane >> 4, l15 = lane & 15;

  // [buf][digit][n(32)][k(64, pad to 80B)]
  __shared__ __align__(16) signed char Blds[2][4][32][80];

  v4i acc[4][2][2];
#pragma unroll
  for (int d = 0; d < 4; ++d)
#pragma unroll
    for (int m = 0; m < 2; ++m)
#pragma unroll
      for (int n = 0; n < 2; ++n) acc[d][m][n] = (v4i){0, 0, 0, 0};

  // staging mapping: thread owns col sn, k-rows skq*4..skq*4+3 of each chunk
  const int sn  = tid & 31;
  const int skq = tid >> 5;        // 0..15
  const float* Wt = W + (size_t)plane * (IN_DIM * H4) + (size_t)(skq * 4) * H4 + ntile * 32 + sn;
  const float* Et = E + (size_t)plane * (IN_DIM * H4) + (size_t)(skq * 4) * H4 + ntile * 32 + sn;

  const signed char* Xp = X + plane * XELEM;
  const int arow0 = wave * 32 + l15;

  // digitize 4 k-consecutive elements, pack per-digit bytes, 4x b32 LDS writes
  auto cw = [&](const float wv[4], const float ev[4], int bf) {
    int pk[4] = {0, 0, 0, 0};
#pragma unroll
    for (int j = 0; j < 4; ++j) {
      float w = wv[j], evv = ev[j];
      float xc = fminf(fmaxf(w, -0.9921875f), 0.9921875f);
      float qv = rintf(xc * 128.f) * 0.0078125f;
      float noise = (evv * maxw) * 0.1f;
      float a = w + ((qv - w) + noise);          // exact jax f32 chain -> w_eff
      float x0 = a * 8.f;    float f0 = rintf(x0); float r0 = x0 - f0;
      float x1 = r0 * 128.f; float f1 = rintf(x1); float r1 = x1 - f1;
      float x2 = r1 * 128.f; float f2 = rintf(x2); float r2 = x2 - f2;
      float x3 = r2 * 128.f; float f3 = rintf(x3);
      pk[0] |= ((int)f0 & 0xff) << (8 * j);
      pk[1] |= ((int)f1 & 0xff) << (8 * j);
      pk[2] |= ((int)f2 & 0xff) << (8 * j);
      pk[3] |= ((int)f3 & 0xff) << (8 * j);
    }
#pragma unroll
    for (int d = 0; d < 4; ++d)
      *(int*)&Blds[bf][d][sn][skq * 4] = pk[d];
  };

  auto loadWE = [&](int ck, float wv[4], float ev[4]) {
    size_t o = (size_t)(ck * 64) * H4;
#pragma unroll
    for (int j = 0; j < 4; ++j) { wv[j] = Wt[o + (size_t)j * H4]; ev[j] = Et[o + (size_t)j * H4]; }
  };

  // ---- prologue ----
  float wA[4], eA[4], wB[4], eB[4];
  loadWE(0, wA, eA);
  loadWE(1, wB, eB);            // stays in flight past cw below
  cw(wA, eA, 0);                // waits only chunk-0 loads
  v4i afr[2], anx[2];
  afr[0] = *(const v4i*)(Xp + (arow0)      * IN_DIM + quad * 16);
  afr[1] = *(const v4i*)(Xp + (arow0 + 16) * IN_DIM + quad * 16);
  anx[0] = *(const v4i*)(Xp + (arow0)      * IN_DIM + 64 + quad * 16);
  anx[1] = *(const v4i*)(Xp + (arow0 + 16) * IN_DIM + 64 + quad * 16);
  SYNC_LDS();

#pragma unroll
  for (int ch = 0; ch < 16; ++ch) {
    const int buf = ch & 1;
    // issue depth-2 prefetch (chunk ch+2) — survives the raw barrier
    float wN[4], eN[4];
    v4i aN[2];
    if (ch < 14) {
      loadWE(ch + 2, wN, eN);
      aN[0] = *(const v4i*)(Xp + (arow0)      * IN_DIM + (ch + 2) * 64 + quad * 16);
      aN[1] = *(const v4i*)(Xp + (arow0 + 16) * IN_DIM + (ch + 2) * 64 + quad * 16);
    }
    // MFMA on current buffer
#pragma unroll
    for (int d = 0; d < 4; ++d) {
#pragma unroll
      for (int ns = 0; ns < 2; ++ns) {
        v4i bfr = *(const v4i*)&Blds[buf][d][ns * 16 + l15][quad * 16];
        acc[d][0][ns] = __builtin_amdgcn_mfma_i32_16x16x64_i8(afr[0], bfr, acc[d][0][ns], 0, 0, 0);
        acc[d][1][ns] = __builtin_amdgcn_mfma_i32_16x16x64_i8(afr[1], bfr, acc[d][1][ns], 0, 0, 0);
      }
    }
    // digitize chunk ch+1 (loaded one iteration ago) into the other buffer
    if (ch < 15) cw(wB, eB, buf ^ 1);
    // rotate staging registers
#pragma unroll
    for (int j = 0; j < 4; ++j) { wB[j] = wN[j]; eB[j] = eN[j]; }
    afr[0] = anx[0]; afr[1] = anx[1];
    anx[0] = aN[0];  anx[1] = aN[1];
    SYNC_LDS();
  }

  // ---- epilogue: exact combine + compare ----
  const double inv = 1.0 / 16777216.0;   // /(8*128^3)
  const double* thp = thresh + (size_t)sp * H4;
  unsigned char* cp = cmp + (size_t)sp * B_DIM * H4;
#pragma unroll
  for (int ms = 0; ms < 2; ++ms) {
#pragma unroll
    for (int ns = 0; ns < 2; ++ns) {
      int col = ntile * 32 + ns * 16 + l15;
      double th = thp[col];
#pragma unroll
      for (int r = 0; r < 4; ++r) {
        long long T = ((long long)acc[0][ms][ns][r] << 21) + ((long long)acc[1][ms][ns][r] << 14)
                    + ((long long)acc[2][ms][ns][r] << 7)  +  (long long)acc[3][ms][ns][r];
        int row = wave * 32 + ms * 16 + quad * 4 + r;
        cp[(size_t)row * H4 + col] = ((double)T * inv > th) ? 1 : 0;
      }
    }
  }
}

// ---------------- Pass C: pointwise LSTM ----------------
__device__ __forceinline__ float pact_(float x, float a) {
  float t = fabsf(x), u = fabsf(t - a);
  float sg = (x > 0.f) ? 0.5f : ((x < 0.f) ? -0.5f : 0.f);
  return sg * ((t - u) + a);
}
__device__ __forceinline__ float quant_(float x, float a) {
  float xr = x / a;
  xr = fminf(fmaxf(xr, -0.9921875f), 0.9921875f);
  return rintf(xr * 128.f) * 0.0078125f * a;
}
__device__ __forceinline__ float sigm_(float x) { return 1.0f / (1.0f + expf(-x)); }

__global__ void k_pointwise(const unsigned char* __restrict__ cmp, const float* __restrict__ cx,
                            const float* a3, const float* a4, const float* a5, const float* a6,
                            const float* a7, const float* a8, const float* a9, const float* a10,
                            const float* a11, float* __restrict__ out) {
  int idx = blockIdx.x * 256 + threadIdx.x;   // 0..262143
  int b = idx >> 10, h = idx & 1023;
  float g[4];
#pragma unroll
  for (int gi = 0; gi < 4; ++gi) {
    int col = gi * 1024 + h;
    float acc = 0.f;
#pragma unroll
    for (int n = 0; n < 4; ++n) {
      int o = (int)cmp[((size_t)(0 * 4 + n) * B_DIM + b) * H4 + col]
            + (int)cmp[((size_t)(1 * 4 + n) * B_DIM + b) * H4 + col];
      float beta = (float)(8 >> n) / 15.0f;
      acc = acc + beta * (float)o;
    }
    g[gi] = acc;
  }
  float fg = quant_(pact_(sigm_(g[2]), a3[0]), a3[0]);
  float ig = quant_(pact_(sigm_(g[0]), a4[0]), a4[0]);
  float ac = quant_(pact_(tanhf(g[1]), a5[0]), a5[0]);
  float og = quant_(pact_(sigm_(g[3]), a6[0]), a6[0]);
  float cxv = cx[idx];
  float gc = quant_(pact_(cxv * fg, a7[0]), a7[0]);
  float ai = quant_(pact_(ig * ac, a8[0]), a8[0]);
  float nc = quant_(pact_(gc + ai, a9[0]), a9[0]);
  float acl = quant_(pact_(tanhf(nc), a10[0]), a10[0]);
  float nh = quant_(pact_(acl * og, a11[0]), a11[0]);
  out[idx] = nh;
  out[XELEM + idx] = nc;
}

extern "C" void kernel_launch(void* const* d_in, const int* in_sizes, int n_in,
                              void* d_out, int out_size, void* d_ws, size_t ws_size,
                              hipStream_t stream) {
  (void)in_sizes; (void)n_in; (void)out_size; (void)ws_size;
  const float* input = (const float*)d_in[0];
  const float* cx    = (const float*)d_in[2];
  const float* wih   = (const float*)d_in[3];
  const float* whh   = (const float*)d_in[4];
  const float* bih   = (const float*)d_in[5];
  const float* bhh   = (const float*)d_in[6];
  const float* ewih  = (const float*)d_in[7];
  const float* ewhh  = (const float*)d_in[8];
  const float* ebih  = (const float*)d_in[9];
  const float* ebhh  = (const float*)d_in[10];
  const float* a1    = (const float*)d_in[11];
  const float* a3    = (const float*)d_in[12];
  const float* a4    = (const float*)d_in[13];
  const float* a5    = (const float*)d_in[14];
  const float* a6    = (const float*)d_in[15];
  const float* a7    = (const float*)d_in[16];
  const float* a8    = (const float*)d_in[17];
  const float* a9    = (const float*)d_in[18];
  const float* a10   = (const float*)d_in[19];
  const float* a11   = (const float*)d_in[20];
  float* out = (float*)d_out;

  char* ws = (char*)d_ws;
  float*         maxm   = (float*)ws;
  double*        thresh = (double*)(ws + WS_THRESH_OFF);
  signed char*   X      = (signed char*)(ws + WS_X_OFF);
  unsigned char* cmp    = (unsigned char*)(ws + WS_CMP_OFF);

  hipMemsetAsync(ws, 0, 64, stream);
  k_max<<<4098, 256, 0, stream>>>(wih, whh, bih, bhh, maxm);
  k_prep<<<1152, 256, 0, stream>>>(input, bih, bhh, ebih, ebhh, a1, maxm, thresh, X);
  k_gemm<<<dim3(128, 8), 512, 0, stream>>>(wih, whh, ewih, ewhh, maxm, thresh, X, cmp);
  k_pointwise<<<1024, 256, 0, stream>>>(cmp, cx, a3, a4, a5, a6, a7, a8, a9, a10, a11, out);
}